// Round 4
// baseline (79.886 us; speedup 1.0000x reference)
//
#include <hip/hip_runtime.h>

#define PI_F 3.14159265358979323846f
// SHARP * log2(e): sigmoid(SHARP*t) = 1/(1 + 2^(-SL*t))
constexpr float SL = 50.0f * 1.44269504089f;

__device__ __forceinline__ float fexp2(float x) {
#if __has_builtin(__builtin_amdgcn_exp2f)
  return __builtin_amdgcn_exp2f(x);
#else
  return __expf(x * 0.69314718056f);
#endif
}
__device__ __forceinline__ float frcp(float x) {
#if __has_builtin(__builtin_amdgcn_rcpf)
  return __builtin_amdgcn_rcpf(x);
#else
  return 1.0f / x;
#endif
}
__device__ __forceinline__ float fsig(float x) {
  return frcp(1.0f + fexp2(-x * 1.44269504089f));
}

// Grid 33x33, block 256 = 4 independent waves. Each wave owns one 16x16
// padded-aligned pixel region (A = 2*by + (wv>>1), B = 2*bx + (wv&1)) and a
// wave-private LDS slice -> NO __syncthreads anywhere: the scheduler can
// overlap the canvas loads with phase-1's serial dec->param->sigmoid chain.
//
// Phase 1 (lanes 0..19 of each wave): prep stroke j (tile k=j/5 in blend
//   order (e,e),(o,o),(o,e),(e,o); stroke j%5), ballot-compact live strokes
//   (decision!=0, order preserved) into the wave's LDS list, <=20 records
//   x 3 float4: {X0,Y0,ct',st'} {thrU,thrV,cR,cG} {cB,-,-,-} where
//   X0 = 16c + 32*x0 (padded px units), ct' = cos*SL/32, thrU = SL*wd/2.
// Phase 2: thread = 1 row x 4 cols (float4 per channel, coalesced); loop
//   over the wave-uniform stroke count; 3x ds_read_b128 broadcast/stroke;
//   u,w advance incrementally across columns.
__global__ __launch_bounds__(256) void render_kernel(
    const float* __restrict__ param, const int* __restrict__ dec,
    const float* __restrict__ canvas, float* __restrict__ out) {
  __shared__ float4 lds4[4][20 * 3];

  const int t = threadIdx.x;
  const int wv = t >> 6;   // wave 0..3
  const int j  = t & 63;   // lane 0..63
  const int A = blockIdx.y * 2 + (wv >> 1);  // padded 16-block row (0..65)
  const int B = blockIdx.x * 2 + (wv & 1);   // padded 16-block col (0..65)
  if (A > 64 || B > 64) return;  // wave-uniform exit (grid over-cover)

  // ---- Canvas loads first (independent of phase 1; overlap latency) ----
  const int cg = j & 3;                 // column group (4 px)
  const int row = j >> 2;               // row within region (0..15)
  const int Xb = B * 16 - 8 + cg * 4;   // output col of float4 base
  const int Yr = A * 16 - 8 + row;      // output row
  const bool valid = ((unsigned)Xb < 1024u) & ((unsigned)Yr < 1024u);
  const size_t pix = valid ? ((size_t)Yr * 1024 + Xb) : 0;  // clamp, no branch
  float4 v0 = *(const float4*)(canvas + pix);
  float4 v1 = *(const float4*)(canvas + pix + 1024 * 1024);
  float4 v2 = *(const float4*)(canvas + pix + 2 * 1024 * 1024);

  // ---- Phase 1: prep (lanes 0..19) ----
  const int re = (A & 1) ? A - 1 : A;
  const int ro = (A & 1) ? A : A - 1;
  const int ce = (B & 1) ? B - 1 : B;
  const int co = (B & 1) ? B : B - 1;

  bool live = false;
  float4 w0q, w1q, w2q;
  if (j < 20) {
    const int k = j / 5;       // tile slot in blend order
    const int i = j - k * 5;   // stroke index within tile
    const int rr = (k == 0 || k == 3) ? re : ro;
    const int cc = (k & 1) ? co : ce;
    if ((unsigned)rr < 64u && (unsigned)cc < 64u) {
      const int sid = (rr * 64 + cc) * 5 + i;
      if (dec[sid] != 0) {
        const float4* p4 = (const float4*)(param + (size_t)sid * 12);
        float4 a = p4[0];  // params 0..3
        float4 b = p4[1];  // params 4..7
        float x0 = fsig(a.x), y0 = fsig(a.y);
        float wd = fmaxf(fsig(a.z), 0.01f);
        float ht = fmaxf(fsig(a.w), 0.01f);
        float th = fsig(b.x) * PI_F;
        float ct = __cosf(th), st = __sinf(th);
        w0q = make_float4((float)(cc * 16) + 32.0f * x0,
                          (float)(rr * 16) + 32.0f * y0,
                          ct * (SL / 32.0f), st * (SL / 32.0f));
        w1q = make_float4(SL * wd * 0.5f, SL * ht * 0.5f,
                          fsig(b.y), fsig(b.z));
        w2q = make_float4(fsig(b.w), 0.0f, 0.0f, 0.0f);
        live = true;
      }
    }
  }
  const unsigned long long mask = __ballot(live);
  const int total = __popcll(mask);  // wave-uniform live-stroke count
  if (live) {
    const int off = __popcll(mask & ((1ull << j) - 1));
    lds4[wv][off * 3 + 0] = w0q;
    lds4[wv][off * 3 + 1] = w1q;
    lds4[wv][off * 3 + 2] = w2q;
  }
  // No barrier: LDS slice is wave-private; in-wave ds ordering via lgkmcnt.

  // ---- Phase 2: composite ----
  const float fx0 = (float)(B * 16 + cg * 4) + 0.5f;  // padded px coords
  const float fy  = (float)(A * 16 + row) + 0.5f;

  for (int s = 0; s < total; ++s) {
    const float4 qa = lds4[wv][s * 3 + 0];
    const float4 qb = lds4[wv][s * 3 + 1];
    const float4 qc = lds4[wv][s * 3 + 2];
    const float dx0 = fx0 - qa.x;
    const float dy  = fy - qa.y;
    float u = dx0 * qa.z + dy * qa.w;   // SL*u at column 0
    float w = dy * qa.z - dx0 * qa.w;   // SL*v at column 0
    float* pv0 = &v0.x;
    float* pv1 = &v1.x;
    float* pv2 = &v2.x;
#pragma unroll
    for (int m = 0; m < 4; ++m) {
      const float e1 = fexp2(fabsf(u) - qb.x);
      const float e2 = fexp2(fabsf(w) - qb.y);
      const float al = frcp((1.0f + e1) * (1.0f + e2));
      pv0[m] = fmaf(al, qb.z - pv0[m], pv0[m]);
      pv1[m] = fmaf(al, qb.w - pv1[m], pv1[m]);
      pv2[m] = fmaf(al, qc.x - pv2[m], pv2[m]);
      u += qa.z;  // next column: dxp += 1
      w -= qa.w;
    }
  }

  if (valid) {
    *(float4*)(out + pix) = v0;
    *(float4*)(out + pix + 1024 * 1024) = v1;
    *(float4*)(out + pix + 2 * 1024 * 1024) = v2;
  }
}

extern "C" void kernel_launch(void* const* d_in, const int* in_sizes, int n_in,
                              void* d_out, int out_size, void* d_ws, size_t ws_size,
                              hipStream_t stream) {
  const float* param  = (const float*)d_in[0];
  const int*   dec    = (const int*)d_in[1];
  const float* canvas = (const float*)d_in[2];
  float* outp = (float*)d_out;
  (void)d_ws; (void)ws_size;

  dim3 grid(33, 33, 1);
  render_kernel<<<grid, 256, 0, stream>>>(param, dec, canvas, outp);
}